// Round 3
// baseline (412.933 us; speedup 1.0000x reference)
//
#include <hip/hip_runtime.h>
#include <hip/hip_bf16.h>
#include <math.h>

// Problem constants
#define HDIM 1024
#define IDIM 4096
#define NE 8
#define NTOK 2048           // B*S
#define PADROWS 256         // tile-overrun padding rows (BM=256)

typedef __attribute__((ext_vector_type(8))) short bf16x8;
typedef __attribute__((ext_vector_type(4))) float f32x4;

__device__ __forceinline__ unsigned int f2bf(float f) {
    unsigned int u = __float_as_uint(f);
    u = (u + 0x7FFFu + ((u >> 16) & 1u)) >> 16;   // RNE
    return u;
}

__device__ __forceinline__ unsigned int pkbf2(float lo, float hi) {
    union { __hip_bfloat162 h; unsigned int u; } cv;
    cv.h = __float22bfloat162_rn(make_float2(lo, hi));   // -> v_cvt_pk_bf16_f32
    return cv.u;
}

__device__ __forceinline__ float comp4(const float4& v, int c) {
    return c == 0 ? v.x : c == 1 ? v.y : c == 2 ? v.z : v.w;  // c is unroll-constant
}

// ---------------- Router: fp64 logits, argmax (first-max tie-break) -------------
__global__ __launch_bounds__(256) void router_k(const float* __restrict__ x,
                                                const float* __restrict__ rw,
                                                const float* __restrict__ rb,
                                                int* __restrict__ eidx,
                                                int* __restrict__ counts) {
    const int wave = threadIdx.x >> 6, lane = threadIdx.x & 63;
    const int t = blockIdx.x * 4 + wave;
    if (t >= NTOK) return;
    double acc[NE];
#pragma unroll
    for (int e = 0; e < NE; e++) acc[e] = 0.0;
    for (int h = lane; h < HDIM; h += 64) {
        double xv = (double)x[(size_t)t * HDIM + h];
        const float4* rwp = (const float4*)&rw[h * NE];
        float4 r0 = rwp[0], r1 = rwp[1];
        acc[0] += xv * (double)r0.x;  acc[1] += xv * (double)r0.y;
        acc[2] += xv * (double)r0.z;  acc[3] += xv * (double)r0.w;
        acc[4] += xv * (double)r1.x;  acc[5] += xv * (double)r1.y;
        acc[6] += xv * (double)r1.z;  acc[7] += xv * (double)r1.w;
    }
#pragma unroll
    for (int m = 32; m >= 1; m >>= 1) {
#pragma unroll
        for (int e = 0; e < NE; e++) acc[e] += __shfl_xor(acc[e], m);
    }
    if (lane == 0) {
        double best = acc[0] + (double)rb[0];
        int be = 0;
#pragma unroll
        for (int e = 1; e < NE; e++) {
            double v = acc[e] + (double)rb[e];
            if (v > best) { best = v; be = e; }
        }
        eidx[t] = be;
        atomicAdd(&counts[be], 1);
    }
}

__global__ void scan_k(const int* __restrict__ counts, int* __restrict__ offsets) {
    if (threadIdx.x == 0 && blockIdx.x == 0) {
        int s = 0;
        for (int e = 0; e < NE; e++) { offsets[e] = s; s += counts[e]; }
        offsets[NE] = s;
    }
}

// ---------------- Gather: Xg[row] = bf16(x[t] + 0.1*game_emb[e]) ----------------
__global__ __launch_bounds__(256) void gather_k(const float* __restrict__ x,
                                                const float* __restrict__ gemb,
                                                const int* __restrict__ eidx,
                                                const int* __restrict__ offsets,
                                                int* __restrict__ cursors,
                                                int* __restrict__ rowmap,
                                                unsigned short* __restrict__ Xg) {
    __shared__ int srow, se;
    const int t = blockIdx.x;
    if (threadIdx.x == 0) {
        int e = eidx[t];
        int pos = atomicAdd(&cursors[e], 1);
        int row = offsets[e] + pos;
        rowmap[row] = t;
        srow = row; se = e;
    }
    __syncthreads();
    const int row = srow, e = se;
    const int c = threadIdx.x * 4;
    float4 xv = *(const float4*)&x[(size_t)t * HDIM + c];
    float4 gv = *(const float4*)&gemb[(size_t)e * HDIM + c];
    ushort4 o;
    o.x = (unsigned short)f2bf(xv.x + 0.1f * gv.x);
    o.y = (unsigned short)f2bf(xv.y + 0.1f * gv.y);
    o.z = (unsigned short)f2bf(xv.z + 0.1f * gv.z);
    o.w = (unsigned short)f2bf(xv.w + 0.1f * gv.w);
    *(ushort4*)&Xg[(size_t)row * HDIM + c] = o;
}

// ---------------- Grouped GEMM (bf16 MFMA), weights read once -------------------
// A: bf16 [rows x lda] gathered. B: f32 [lda x ldbN] per expert.
// 512 threads, 8 waves (WRWS x WCLS). BM=256 covers a whole expert -> each weight
// element fetched once. EPI 0: Hout = bf16(gelu(acc+b1)).
// EPI 1: atomicAdd(Yout[rowmap[row]], acc (+bias if split 0)); split-K fused in z.
template<int BM, int BN, int WRWS, int WCLS, int EPI>
__global__ __launch_bounds__(512, 2) void moe_gemm_k(
        const unsigned short* __restrict__ A, int lda,
        int ksplit,
        const float* __restrict__ Bw, int ldbN,
        const float* __restrict__ bias,
        const int* __restrict__ offsets,
        const int* __restrict__ rowmap,
        unsigned short* __restrict__ Hout,
        float* __restrict__ Yout) {
    constexpr int THREADS = 512;
    constexpr int MFRAG = BM / (WRWS * 16);
    constexpr int NFRAG = BN / (WCLS * 16);
    constexpr int ACH = BM * 8 / THREADS;   // A 16B chunks per thread
    constexpr int QPR = BN / 4;             // B float4 quads per k-row
    constexpr int RPT = BN / 32;            // B k-rows per thread

    __shared__ __align__(16) unsigned short At[BM * 64];
    __shared__ __align__(16) unsigned short Bt[8 * BN * 8];

    const int e = blockIdx.z & 7;
    const int split = blockIdx.z >> 3;
    const int rend = offsets[e + 1];
    const int r0 = offsets[e] + blockIdx.y * BM;
    if (r0 >= rend) return;
    const int c0 = blockIdx.x * BN;
    const int kbeg = split * ksplit;
    const int kend = kbeg + ksplit;
    const float* Be = Bw + (size_t)e * lda * ldbN;

    const int tid = threadIdx.x;
    const int wave = tid >> 6, lane = tid & 63;
    const int wr = (wave / WCLS) * (MFRAG * 16);
    const int wc = (wave % WCLS) * (NFRAG * 16);
    const int l15 = lane & 15, l4 = lane >> 4;

    // B staging coords: thread loads RPT consecutive k-rows x 4 cols (float4)
    const int bcol4 = (tid % QPR) * 4;
    const int brow0 = (tid / QPR) * RPT;
    const int bkb = brow0 >> 3;
    const int bsub = brow0 & 7;

    const float* bp = Be + (size_t)(kbeg + brow0) * ldbN + c0 + bcol4;
    const unsigned short* ap[ACH];
#pragma unroll
    for (int p = 0; p < ACH; p++) {
        int cid = p * THREADS + tid;
        int row = cid >> 3, ks = cid & 7;
        ap[p] = &A[(size_t)(r0 + row) * lda + kbeg + ((ks ^ (row & 7)) << 3)];
    }

    f32x4 acc[MFRAG][NFRAG];
#pragma unroll
    for (int m = 0; m < MFRAG; m++)
#pragma unroll
        for (int n = 0; n < NFRAG; n++) acc[m][n] = (f32x4){0.f, 0.f, 0.f, 0.f};

    float4 bv[RPT];
    uint4  av[ACH];
#define LOAD_AB() do {                                                          \
            _Pragma("unroll")                                                   \
            for (int j = 0; j < RPT; j++)                                       \
                bv[j] = *(const float4*)&bp[(size_t)j * ldbN];                  \
            bp += (size_t)64 * ldbN;                                            \
            _Pragma("unroll")                                                   \
            for (int p = 0; p < ACH; p++) { av[p] = *(const uint4*)ap[p]; ap[p] += 64; } \
        } while (0)

    LOAD_AB();
    for (int k0 = kbeg; k0 < kend; k0 += 64) {
        // A -> LDS (linear dest, k-slot content pre-swizzled)
#pragma unroll
        for (int p = 0; p < ACH; p++) {
            int cid = p * THREADS + tid;
            *(uint4*)&At[cid * 8] = av[p];
        }
        // B pack f32->bf16 -> LDS [kb][col-slot][8]
#pragma unroll
        for (int c = 0; c < 4; c++) {
            unsigned int pk[RPT / 2];
#pragma unroll
            for (int j = 0; j < RPT / 2; j++)
                pk[j] = pkbf2(comp4(bv[2 * j], c), comp4(bv[2 * j + 1], c));
            int col = bcol4 + c;
            int slot = col ^ ((col >> 3) & 7);
            unsigned short* dst = &Bt[(bkb * BN + slot) * 8 + bsub];
            if constexpr (RPT == 8) {
                uint4 w; w.x = pk[0]; w.y = pk[1]; w.z = pk[2]; w.w = pk[3];
                *(uint4*)dst = w;
            } else if constexpr (RPT == 4) {
                uint2 w; w.x = pk[0]; w.y = pk[1];
                *(uint2*)dst = w;
            } else {
                *(unsigned int*)dst = pk[0];
            }
        }
        __syncthreads();
        if (k0 + 64 < kend) LOAD_AB();   // next step's loads in flight during MFMA
#pragma unroll
        for (int kh = 0; kh < 2; kh++) {
            const int kb = kh * 4 + l4;
            bf16x8 af[MFRAG], bfr[NFRAG];
#pragma unroll
            for (int m = 0; m < MFRAG; m++) {
                int row = wr + m * 16 + l15;
                af[m] = *(const bf16x8*)&At[row * 64 + ((kb ^ (row & 7)) << 3)];
            }
#pragma unroll
            for (int n = 0; n < NFRAG; n++) {
                int col = wc + n * 16 + l15;
                int slot = col ^ ((col >> 3) & 7);
                bfr[n] = *(const bf16x8*)&Bt[(kb * BN + slot) * 8];
            }
#pragma unroll
            for (int m = 0; m < MFRAG; m++)
#pragma unroll
                for (int n = 0; n < NFRAG; n++)
                    acc[m][n] = __builtin_amdgcn_mfma_f32_16x16x32_bf16(af[m], bfr[n], acc[m][n], 0, 0, 0);
        }
        __syncthreads();
    }
#undef LOAD_AB

    // ---- epilogue ----
#pragma unroll
    for (int m = 0; m < MFRAG; m++) {
#pragma unroll
        for (int r = 0; r < 4; r++) {
            const int row = r0 + wr + m * 16 + l4 * 4 + r;
            if (row < rend) {
                if (EPI == 0) {
#pragma unroll
                    for (int n = 0; n < NFRAG; n++) {
                        int col = c0 + wc + n * 16 + l15;
                        float v = acc[m][n][r] + bias[(size_t)e * ldbN + col];
                        float g = 0.5f * v * (1.0f + erff(v * 0.70710678118654752f));
                        Hout[(size_t)row * IDIM + col] = (unsigned short)f2bf(g);
                    }
                } else {
                    const int t = rowmap[row];
#pragma unroll
                    for (int n = 0; n < NFRAG; n++) {
                        int col = c0 + wc + n * 16 + l15;
                        float v = acc[m][n][r];
                        if (split == 0) v += bias[(size_t)e * ldbN + col];
                        atomicAdd(&Yout[(size_t)t * HDIM + col], v);
                    }
                }
            }
        }
    }
}

// ---------------- launch ---------------------------------------------------------
extern "C" void kernel_launch(void* const* d_in, const int* in_sizes, int n_in,
                              void* d_out, int out_size, void* d_ws, size_t ws_size,
                              hipStream_t stream) {
    const float* x    = (const float*)d_in[0];
    const float* rw   = (const float*)d_in[1];
    const float* rb   = (const float*)d_in[2];
    const float* w1   = (const float*)d_in[3];
    const float* b1   = (const float*)d_in[4];
    const float* w2   = (const float*)d_in[5];
    const float* b2   = (const float*)d_in[6];
    const float* gemb = (const float*)d_in[7];
    float* out = (float*)d_out;

    // workspace layout: meta | Xg | Hbuf   (~23.6 MB)
    char* ws = (char*)d_ws;
    int* meta    = (int*)ws;
    int* counts  = meta;            // 8
    int* cursors = meta + 8;        // 8
    int* offsets = meta + 16;       // 9
    int* eidx    = meta + 32;       // 2048
    int* rowmap  = meta + 32 + NTOK;
    size_t off = 32768;
    unsigned short* Xg = (unsigned short*)(ws + off);
    off += (size_t)(NTOK + PADROWS) * HDIM * 2;
    unsigned short* Hbuf = (unsigned short*)(ws + off);

    hipMemsetAsync(counts, 0, 16 * sizeof(int), stream);   // counts + cursors
    hipMemsetAsync(out, 0, (size_t)NTOK * HDIM * sizeof(float), stream);
    router_k<<<NTOK / 4, 256, 0, stream>>>(x, rw, rb, eidx, counts);
    scan_k<<<1, 64, 0, stream>>>(counts, offsets);
    gather_k<<<NTOK, 256, 0, stream>>>(x, gemb, eidx, offsets, cursors, rowmap, Xg);
    // FFN1: [rows x 1024] @ w1[e] -> gelu -> Hbuf (bf16). One row-block per expert.
    moe_gemm_k<256, 128, 4, 2, 0><<<dim3(IDIM / 128, NTOK / 256, NE), 512, 0, stream>>>(
        Xg, HDIM, HDIM, w1, IDIM, b1, offsets, rowmap, Hbuf, nullptr);
    // FFN2: [rows x 4096] @ w2[e] + b2 -> atomicAdd out (split-K=2 in z)
    moe_gemm_k<256, 64, 4, 2, 1><<<dim3(HDIM / 64, NTOK / 256, NE * 2), 512, 0, stream>>>(
        Hbuf, IDIM, IDIM / 2, w2, HDIM, b2, offsets, rowmap, nullptr, out);
}

// Round 4
// 264.540 us; speedup vs baseline: 1.5609x; 1.5609x over previous
//
#include <hip/hip_runtime.h>
#include <hip/hip_bf16.h>
#include <math.h>

#define HDIM 1024
#define IDIM 4096
#define NE 8
#define NTOK 2048
#define PADROWS 256

typedef __attribute__((ext_vector_type(8))) short bf16x8;
typedef __attribute__((ext_vector_type(4))) float f32x4;

__device__ __forceinline__ unsigned int f2bf(float f) {
    unsigned int u = __float_as_uint(f);
    u = (u + 0x7FFFu + ((u >> 16) & 1u)) >> 16;   // RNE
    return u;
}

__device__ __forceinline__ unsigned int pkbf2(float lo, float hi) {
    union { __hip_bfloat162 h; unsigned int u; } cv;
    cv.h = __float22bfloat162_rn(make_float2(lo, hi));   // v_cvt_pk_bf16_f32
    return cv.u;
}

template<typename T, typename U>
__device__ __forceinline__ void gld16(const T* g, U* l) {
    __builtin_amdgcn_global_load_lds((const __attribute__((address_space(1))) void*)g,
                                     (__attribute__((address_space(3))) void*)l, 16, 0, 0);
}

template<int N> __device__ __forceinline__ void waitvm() {
    static_assert(N == 0 || N == 5 || N == 8, "add literal case");
    if constexpr (N == 0)      asm volatile("s_waitcnt vmcnt(0)" ::: "memory");
    else if constexpr (N == 5) asm volatile("s_waitcnt vmcnt(5)" ::: "memory");
    else if constexpr (N == 8) asm volatile("s_waitcnt vmcnt(8)" ::: "memory");
}

// ---------------- Router: fp64 logits, argmax (first-max tie-break) -------------
__global__ __launch_bounds__(256) void router_k(const float* __restrict__ x,
                                                const float* __restrict__ rw,
                                                const float* __restrict__ rb,
                                                int* __restrict__ eidx,
                                                int* __restrict__ counts) {
    const int wave = threadIdx.x >> 6, lane = threadIdx.x & 63;
    const int t = blockIdx.x * 4 + wave;
    if (t >= NTOK) return;
    double acc[NE];
#pragma unroll
    for (int e = 0; e < NE; e++) acc[e] = 0.0;
    for (int h = lane; h < HDIM; h += 64) {
        double xv = (double)x[(size_t)t * HDIM + h];
        const float4* rwp = (const float4*)&rw[h * NE];
        float4 r0 = rwp[0], r1 = rwp[1];
        acc[0] += xv * (double)r0.x;  acc[1] += xv * (double)r0.y;
        acc[2] += xv * (double)r0.z;  acc[3] += xv * (double)r0.w;
        acc[4] += xv * (double)r1.x;  acc[5] += xv * (double)r1.y;
        acc[6] += xv * (double)r1.z;  acc[7] += xv * (double)r1.w;
    }
#pragma unroll
    for (int m = 32; m >= 1; m >>= 1) {
#pragma unroll
        for (int e = 0; e < NE; e++) acc[e] += __shfl_xor(acc[e], m);
    }
    if (lane == 0) {
        double best = acc[0] + (double)rb[0];
        int be = 0;
#pragma unroll
        for (int e = 1; e < NE; e++) {
            double v = acc[e] + (double)rb[e];
            if (v > best) { best = v; be = e; }
        }
        eidx[t] = be;
        atomicAdd(&counts[be], 1);
    }
}

__global__ void scan_k(const int* __restrict__ counts, int* __restrict__ offsets) {
    if (threadIdx.x == 0 && blockIdx.x == 0) {
        int s = 0;
        for (int e = 0; e < NE; e++) { offsets[e] = s; s += counts[e]; }
        offsets[NE] = s;
    }
}

// ---------------- Gather: Xg[row] = bf16(x[t] + 0.1*game_emb[e]) ----------------
__global__ __launch_bounds__(256) void gather_k(const float* __restrict__ x,
                                                const float* __restrict__ gemb,
                                                const int* __restrict__ eidx,
                                                const int* __restrict__ offsets,
                                                int* __restrict__ cursors,
                                                int* __restrict__ rowmap,
                                                unsigned short* __restrict__ Xg) {
    __shared__ int srow, se;
    const int t = blockIdx.x;
    if (threadIdx.x == 0) {
        int e = eidx[t];
        int pos = atomicAdd(&cursors[e], 1);
        int row = offsets[e] + pos;
        rowmap[row] = t;
        srow = row; se = e;
    }
    __syncthreads();
    const int row = srow, e = se;
    const int c = threadIdx.x * 4;
    float4 xv = *(const float4*)&x[(size_t)t * HDIM + c];
    float4 gv = *(const float4*)&gemb[(size_t)e * HDIM + c];
    ushort4 o;
    o.x = (unsigned short)f2bf(xv.x + 0.1f * gv.x);
    o.y = (unsigned short)f2bf(xv.y + 0.1f * gv.y);
    o.z = (unsigned short)f2bf(xv.z + 0.1f * gv.z);
    o.w = (unsigned short)f2bf(xv.w + 0.1f * gv.w);
    *(ushort4*)&Xg[(size_t)row * HDIM + c] = o;
}

// ---------------- Grouped GEMM: global_load_lds dbuf + counted vmcnt ------------
// A bf16 [rows x lda]; B f32 [Kfull x ldbN] per expert, staged RAW f32 into LDS,
// transposed + converted to bf16 at fragment-read time.
// 8 waves (4x2). BM=256 covers a whole expert -> weights fetched once.
// EPI 0: Hout = bf16(gelu(acc+b1)).
// EPI 1: split0 -> Yout[rowmap[row]] = acc+bias (direct store); split1 -> Pout raw.
template<int BM, int BN, int EPI>
__global__ __launch_bounds__(512, 2) void moe_gemm_k(
        const unsigned short* __restrict__ A, int lda, int Kfull, int ksplit,
        const float* __restrict__ Bw, int ldbN,
        const float* __restrict__ bias,
        const int* __restrict__ offsets, const int* __restrict__ rowmap,
        unsigned short* __restrict__ Hout, float* __restrict__ Yout,
        float* __restrict__ Pout) {
    constexpr int MFRAG = BM / 64;     // 4 (wave rows = 4)
    constexpr int NFRAG = BN / 32;     // 4 (G1) / 1 (G2)  (wave cols = 2)
    constexpr int NIA = BM / 64;       // global_load_lds instrs per wave (A)
    constexpr int NIB = BN / 32;       // per wave (B)
    constexpr int GPK = BN / 4;        // 16B granules per B k-row

    __shared__ unsigned short At[2][BM * 64];
    __shared__ float Bt[2][64 * BN];

    const int e = blockIdx.z & 7;
    const int split = blockIdx.z >> 3;
    const int rend = offsets[e + 1];
    const int r0 = offsets[e] + blockIdx.y * BM;
    if (r0 >= rend) return;
    const int c0 = blockIdx.x * BN;
    const int kbeg = split * ksplit;
    const int nt = ksplit / 64;
    const float* Be = Bw + (size_t)e * Kfull * ldbN;

    const int tid = threadIdx.x;
    const int wave = tid >> 6, lane = tid & 63;
    const int wr = (wave >> 1) * (MFRAG * 16);
    const int wc = (wave & 1) * (NFRAG * 16);
    const int l15 = lane & 15, l4 = lane >> 4;

    // stage one K-step (64 k) into buffer b via async DMA.
    // A LDS granule g=(row,pkb): content k-slot kb = pkb^(row&7)  (XOR both-sides)
    // B LDS granule g=(k,cg):    content src col-granule cg^(((k>>3)&1)<<2)
    auto stage = [&](int b, int kglob) {
#pragma unroll
        for (int i = 0; i < NIA; ++i) {
            int gb = (wave * NIA + i) << 6;
            int g = gb + lane;
            int row = g >> 3, pkb = g & 7;
            const unsigned short* src =
                A + (size_t)(r0 + row) * lda + kglob + ((pkb ^ (row & 7)) << 3);
            gld16(src, &At[b][(size_t)gb * 8]);
        }
#pragma unroll
        for (int i = 0; i < NIB; ++i) {
            int gb = (wave * NIB + i) << 6;
            int g = gb + lane;
            int k = g / GPK, cg = g % GPK;
            int scg = cg ^ (((k >> 3) & 1) << 2);
            const float* src = Be + (size_t)(kglob + k) * ldbN + c0 + (scg << 2);
            gld16(src, &Bt[b][(size_t)gb * 4]);
        }
    };

    f32x4 acc[MFRAG][NFRAG] = {};

    stage(0, kbeg);
    for (int t = 0; t < nt; ++t) {
        const int cur = t & 1;
        if (t + 1 < nt) {
            stage(cur ^ 1, kbeg + (t + 1) * 64);   // next step's loads stay in flight
            waitvm<NIA + NIB>();                   // only wait for CURRENT step's loads
        } else {
            waitvm<0>();
        }
        __builtin_amdgcn_s_barrier();
        __builtin_amdgcn_sched_barrier(0);
#pragma unroll
        for (int kh = 0; kh < 2; ++kh) {
            const int kb = kh * 4 + l4;
            bf16x8 af[MFRAG];
#pragma unroll
            for (int m = 0; m < MFRAG; ++m) {
                int row = wr + m * 16 + l15;
                af[m] = *(const bf16x8*)&At[cur][(row * 8 + (kb ^ (row & 7))) * 8];
            }
#pragma unroll
            for (int n = 0; n < NFRAG; ++n) {
                int cswz = (wc + n * 16 + l15) ^ ((kb & 1) << 4);
                float f[8];
#pragma unroll
                for (int j = 0; j < 8; ++j)
                    f[j] = Bt[cur][(kb * 8 + j) * BN + cswz];
                bf16x8 bfr;
                unsigned int* bu = (unsigned int*)&bfr;
#pragma unroll
                for (int j = 0; j < 4; ++j) bu[j] = pkbf2(f[2 * j], f[2 * j + 1]);
#pragma unroll
                for (int m = 0; m < MFRAG; ++m)
                    acc[m][n] = __builtin_amdgcn_mfma_f32_16x16x32_bf16(af[m], bfr, acc[m][n], 0, 0, 0);
            }
        }
        __builtin_amdgcn_sched_barrier(0);
        __builtin_amdgcn_s_barrier();
    }

    // ---- epilogue ----
#pragma unroll
    for (int m = 0; m < MFRAG; ++m) {
#pragma unroll
        for (int r = 0; r < 4; ++r) {
            const int row = r0 + wr + m * 16 + l4 * 4 + r;
            if (row < rend) {
                if constexpr (EPI == 0) {
#pragma unroll
                    for (int n = 0; n < NFRAG; ++n) {
                        int col = c0 + wc + n * 16 + l15;
                        float v = acc[m][n][r] + bias[(size_t)e * ldbN + col];
                        float g = 0.5f * v * (1.0f + erff(v * 0.70710678118654752f));
                        Hout[(size_t)row * IDIM + col] = (unsigned short)f2bf(g);
                    }
                } else if (split == 0) {
                    const int tt = rowmap[row];
#pragma unroll
                    for (int n = 0; n < NFRAG; ++n) {
                        int col = c0 + wc + n * 16 + l15;
                        Yout[(size_t)tt * HDIM + col] = acc[m][n][r] + bias[(size_t)e * ldbN + col];
                    }
                } else {
#pragma unroll
                    for (int n = 0; n < NFRAG; ++n) {
                        int col = c0 + wc + n * 16 + l15;
                        Pout[(size_t)row * HDIM + col] = acc[m][n][r];
                    }
                }
            }
        }
    }
}

// ---------------- split-K combine: out[t] += P[row] ------------------------------
__global__ __launch_bounds__(256) void reduce_k(const float* __restrict__ P,
                                                const int* __restrict__ rowmap,
                                                float* __restrict__ out) {
    const int row = blockIdx.x;
    const int t = rowmap[row];
    const int c = threadIdx.x * 4;
    float4 p = *(const float4*)&P[(size_t)row * HDIM + c];
    float4 o = *(const float4*)&out[(size_t)t * HDIM + c];
    o.x += p.x; o.y += p.y; o.z += p.z; o.w += p.w;
    *(float4*)&out[(size_t)t * HDIM + c] = o;
}

// ---------------- launch ---------------------------------------------------------
extern "C" void kernel_launch(void* const* d_in, const int* in_sizes, int n_in,
                              void* d_out, int out_size, void* d_ws, size_t ws_size,
                              hipStream_t stream) {
    const float* x    = (const float*)d_in[0];
    const float* rw   = (const float*)d_in[1];
    const float* rb   = (const float*)d_in[2];
    const float* w1   = (const float*)d_in[3];
    const float* b1   = (const float*)d_in[4];
    const float* w2   = (const float*)d_in[5];
    const float* b2   = (const float*)d_in[6];
    const float* gemb = (const float*)d_in[7];
    float* out = (float*)d_out;

    // workspace: meta | Xg | Hbuf | P
    char* ws = (char*)d_ws;
    int* meta    = (int*)ws;
    int* counts  = meta;            // 8
    int* cursors = meta + 8;        // 8
    int* offsets = meta + 16;       // 9
    int* eidx    = meta + 32;       // 2048
    int* rowmap  = meta + 32 + NTOK;
    size_t off = 32768;
    unsigned short* Xg = (unsigned short*)(ws + off);
    off += (size_t)(NTOK + PADROWS) * HDIM * 2;
    unsigned short* Hbuf = (unsigned short*)(ws + off);
    off += (size_t)(NTOK + PADROWS) * IDIM * 2;
    float* P = (float*)(ws + off);
    size_t need = off + (size_t)NTOK * HDIM * 4;
    const int nsplit = (ws_size >= need) ? 2 : 1;

    hipMemsetAsync(counts, 0, 16 * sizeof(int), stream);
    router_k<<<NTOK / 4, 256, 0, stream>>>(x, rw, rb, eidx, counts);
    scan_k<<<1, 64, 0, stream>>>(counts, offsets);
    gather_k<<<NTOK, 256, 0, stream>>>(x, gemb, eidx, offsets, cursors, rowmap, Xg);
    // FFN1: [rows x 1024] @ w1[e] -> gelu -> Hbuf (bf16). 256 blocks, 128KB LDS.
    moe_gemm_k<256, 128, 0><<<dim3(IDIM / 128, NTOK / 256, NE), 512, 0, stream>>>(
        Xg, HDIM, HDIM, HDIM, w1, IDIM, b1, offsets, rowmap, Hbuf, nullptr, nullptr);
    // FFN2: [rows x 4096] @ w2[e] + b2 -> out (split-K in z, direct stores)
    moe_gemm_k<256, 32, 1><<<dim3(HDIM / 32, NTOK / 256, NE * nsplit), 512, 0, stream>>>(
        Hbuf, IDIM, IDIM, IDIM / nsplit, w2, HDIM, b2, offsets, rowmap, nullptr, out, P);
    if (nsplit == 2)
        reduce_k<<<NTOK, 256, 0, stream>>>(P, rowmap, out);
}